// Round 12
// baseline (172.783 us; speedup 1.0000x reference)
//
#include <hip/hip_runtime.h>

typedef __attribute__((ext_vector_type(8))) short short8;
typedef __attribute__((ext_vector_type(4))) float floatx4;
typedef __attribute__((ext_vector_type(2))) unsigned int uintx2;
typedef __attribute__((ext_vector_type(4))) unsigned int uintx4;

#define MFMA16(a, b, c) __builtin_amdgcn_mfma_f32_16x16x32_bf16((a), (b), (c), 0, 0, 0)

#define LDP 80       // P row stride (ushort); 40 dw == 8 mod 32 (measured best)
#define LDO 264      // O-tile LDS row stride (ushort)
#define LOG2E 1.4426950408889634f
#define PSHIFT 23.083120654223414f  // 16*log2(e); Wq/bq pre-scaled by log2(e)

__device__ __forceinline__ float bf2f(unsigned short u) {
  return __uint_as_float(((unsigned int)u) << 16);
}
__device__ __forceinline__ unsigned short f2bf(float f) {
  unsigned int x = __float_as_uint(f);
  x += 0x7FFFu + ((x >> 16) & 1u);   // RNE; finite inputs
  return (unsigned short)(x >> 16);
}
// packed f32x2 -> bf16x2, RNE (same rounding as f2bf)
__device__ __forceinline__ unsigned int cvt_pk_bf16(float lo, float hi) {
  unsigned int r;
  asm("v_cvt_pk_bf16_f32 %0, %1, %2" : "=v"(r) : "v"(lo), "v"(hi));
  return r;
}
__device__ __forceinline__ float ld_in(const void* p, long i, int isf32) {
  if (isf32) return ((const float*)p)[i];
  return bf2f(((const unsigned short*)p)[i]);
}
__device__ __forceinline__ short8 ld16(const unsigned short* p) {
  return *(const short8*)__builtin_assume_aligned(p, 16);
}
__device__ __forceinline__ void st16(unsigned short* p, short8 v) {
  *(short8*)__builtin_assume_aligned(p, 16) = v;
}
__device__ __forceinline__ int detect_bad(const unsigned short* x, int idx) {
  const short8 v = ld16(x + (long)idx * 8);
  int bad = 0;
#pragma unroll
  for (int j = 0; j < 8; j++) {
    const unsigned int e = (((unsigned short)v[j]) >> 7) & 0xFFu;
    if (e >= 141u) bad = 1;
  }
  return bad;
}

// ===========================================================================
// FRAG-MAJOR layouts (all bf16, 1 KB per fragment, lane-ordered):
//  Qf/Kf: A/B-frag of 16 rows(keys) x 32 ch. frag id = (b*4096+row)/16.
//         addr = fid*512 + lane*8   (lane = quad*16 + l15; l15=row, quad=ch/8)
//  Vf:    B-frag of 16 ch x 32 keys. fid = (b*64+kt)*32 + chgrp*2 + kh.
//  Wf_qk: B-frag 16 out x 32 in. fid = tn*8 + ks  (tn 0..3: Q0,Q1,K0,K1)
//  Wf_v:  B-frag 16 out x 32 in. fid = og*8 + ks  (og 0..15)
//  Wf_o:  B-frag 16 out x 32 in. fid = og*8 + ks  (og 0..15)
// ===========================================================================

// ---------------------------------------------------------------------------
// Kernel 0: one-shot weight prep + isf32 flag publish.
// 36 blocks x 256: 0..15 Wo, 16..31 Wv, 32..35 Wq|Wk (Q pre-scaled log2e).
// ---------------------------------------------------------------------------
__global__ __launch_bounds__(256)
void prep_kernel(const void* __restrict__ x,
                 const void* __restrict__ Wq, const void* __restrict__ Wk,
                 const void* __restrict__ Wv, const void* __restrict__ Wo,
                 unsigned short* __restrict__ Wf_qk,
                 unsigned short* __restrict__ Wf_v,
                 unsigned short* __restrict__ Wf_o,
                 int* __restrict__ flagout) {
  __shared__ unsigned short Vl[64][LDP];
  __shared__ int flagl[4];
  const int t = (int)threadIdx.x;
  const int wave = t >> 6, lane = t & 63;
  {
    const int bad = detect_bad((const unsigned short*)x, t) |
                    detect_bad((const unsigned short*)x, 256 + t);
    if (lane == 0) flagl[wave] = (__ballot(bad) != 0ull) ? 1 : 0;
  }
  __syncthreads();
  const int isf32 = flagl[0] | flagl[1] | flagl[2] | flagl[3];
  if (t == 0) flagout[0] = isf32;   // all blocks write same value -- benign

  const int blk = (int)blockIdx.x;
  const int j = t & 63, r4 = t >> 6;

  if (blk < 32) {            // ---- Wo / Wv: 64out x 64in transpose tiles ----
    const void* W = (blk < 16) ? Wo : Wv;
    unsigned short* dst = (blk < 16) ? Wf_o : Wf_v;
    const int b2 = blk & 15;
    const int g0 = (b2 >> 2) * 64, c0 = (b2 & 3) * 64;   // g0: out, c0: in
#pragma unroll
    for (int k2 = 0; k2 < 16; k2++) {
      const int rr = r4 * 16 + k2;
      Vl[j][rr] = f2bf(ld_in(W, (long)(c0 + rr) * 256 + g0 + j, isf32));
    }
    __syncthreads();
#pragma unroll
    for (int cc = 0; cc < 2; cc++) {
      const int c = t + cc * 256;
      const int f_l = c >> 6, lane_c = c & 63;
      const int og = f_l >> 1, kse = f_l & 1;
      const int out_l = lane_c & 15, q = lane_c >> 4;
      const short8 v = ld16(&Vl[og * 16 + out_l][kse * 32 + q * 8]);
      st16(dst + (long)(((g0 >> 4) + og) * 8 + (c0 >> 5) + kse) * 512 + lane_c * 8, v);
    }
  } else {                   // ---- Wq|Wk combined: 64 "out" x 64 in ----
    const int c0 = (blk - 32) * 64;
#pragma unroll
    for (int k2 = 0; k2 < 16; k2++) {
      const int cl = r4 * 16 + k2;
      const float v = (j < 32) ? ld_in(Wq, (long)(c0 + cl) * 32 + j, isf32) * LOG2E
                               : ld_in(Wk, (long)(c0 + cl) * 32 + (j - 32), isf32);
      Vl[j][cl] = f2bf(v);
    }
    __syncthreads();
#pragma unroll
    for (int cc = 0; cc < 2; cc++) {
      const int c = t + cc * 256;
      const int f_l = c >> 6, lane_c = c & 63;
      const int og = f_l >> 1, kse = f_l & 1;
      const int out_l = lane_c & 15, q = lane_c >> 4;
      const short8 v = ld16(&Vl[og * 16 + out_l][kse * 32 + q * 8]);
      st16(Wf_qk + (long)(og * 8 + (c0 >> 5) + kse) * 512 + lane_c * 8, v);
    }
  }
}

// ---------------------------------------------------------------------------
// Kernel 1: projection — R3 measured-best shape (1280 blocks x 256,
// ct = blk>>8, tile = blk&255), detect replaced by prep's flag.
// ---------------------------------------------------------------------------
__global__ __launch_bounds__(256)
void proj_kernel(const void* __restrict__ x,
                 const void* __restrict__ bq, const void* __restrict__ bk,
                 const void* __restrict__ bv,
                 const unsigned short* __restrict__ Wf_qk,
                 const unsigned short* __restrict__ Wf_v,
                 const int* __restrict__ flag,
                 unsigned short* __restrict__ Qf, unsigned short* __restrict__ Kf,
                 unsigned short* __restrict__ Vf) {
  __shared__ unsigned short Vl[64][LDP];   // transpose buffer
  const int t = (int)threadIdx.x;
  const int wave = t >> 6, lane = t & 63, quad = lane >> 4, l15 = lane & 15;

  const int isf32 = flag[0];

  const int blk = (int)blockIdx.x;
  const int ct = blk >> 8;                      // 0..4
  const long row_base = (long)(blk & 255) * 64; // = b*4096 + n0
  const long arow = row_base + wave * 16 + l15;

  const unsigned short* wb = (ct == 0) ? Wf_qk
                                       : (Wf_v + (long)(ct - 1) * 4 * 8 * 512);

  floatx4 acc[4];
  acc[0] = acc[1] = acc[2] = acc[3] = (floatx4)0.0f;

#pragma unroll
  for (int ks = 0; ks < 8; ks++) {
    short8 a;
    if (isf32) {
      const float* xf = (const float*)x + arow * 256 + ks * 32 + quad * 8;
      const floatx4 f0 = *(const floatx4*)xf;
      const floatx4 f1 = *(const floatx4*)(xf + 4);
      uintx4 u;
      u[0] = cvt_pk_bf16(f0[0], f0[1]); u[1] = cvt_pk_bf16(f0[2], f0[3]);
      u[2] = cvt_pk_bf16(f1[0], f1[1]); u[3] = cvt_pk_bf16(f1[2], f1[3]);
      a = *(short8*)&u;
    } else {
      a = ld16((const unsigned short*)x + arow * 256 + ks * 32 + quad * 8);
    }
#pragma unroll
    for (int tn = 0; tn < 4; tn++) {
      const short8 bfr = ld16(wb + (long)(tn * 8 + ks) * 512 + lane * 8);
      acc[tn] = MFMA16(a, bfr, acc[tn]);
    }
  }

  if (ct == 0) {
    // Vl[row][g]: g 0..31 = Q (log2e-scaled), 32..63 = K
#pragma unroll
    for (int tn = 0; tn < 4; tn++) {
      const int g = tn * 16 + l15;
      const float bias = (g < 32) ? ld_in(bq, g, isf32) * LOG2E
                                  : ld_in(bk, g - 32, isf32);
#pragma unroll
      for (int r = 0; r < 4; r++)
        Vl[wave * 16 + quad * 4 + r][g] = f2bf(fmaxf(acc[tn][r] + bias, 0.0f));
    }
    __syncthreads();
    const long f0 = row_base >> 4;
#pragma unroll
    for (int cc = 0; cc < 2; cc++) {
      const int c = t + cc * 256;                  // 0..511
      const int isK = c >> 8;
      const int c2 = c & 255;
      const int f_l = c2 >> 6, lane_c = c2 & 63;
      const int row_l = lane_c & 15, q = lane_c >> 4;
      const short8 v = ld16(&Vl[f_l * 16 + row_l][isK * 32 + q * 8]);
      unsigned short* dst = isK ? Kf : Qf;
      st16(dst + (f0 + f_l) * 512 + lane_c * 8, v);
    }
  } else {
#pragma unroll
    for (int tn = 0; tn < 4; tn++) {
      const float bias = ld_in(bv, (long)(ct - 1) * 64 + tn * 16 + l15, isf32);
#pragma unroll
      for (int r = 0; r < 4; r++)
        Vl[tn * 16 + l15][wave * 16 + quad * 4 + r] =   // [ch_local][key_local]
            f2bf(fmaxf(acc[tn][r] + bias, 0.0f));
    }
    __syncthreads();
    const long bb = row_base >> 12;
    const int kt = (int)((row_base & 4095) >> 6);
    const long fbase = (bb * 64 + kt) * 32 + (long)(ct - 1) * 8;
#pragma unroll
    for (int cc = 0; cc < 2; cc++) {
      const int c = t * 2 + cc;                    // 0..511
      const int f_l = c >> 6, lane_c = c & 63;
      const int cg = f_l >> 1, kh = f_l & 1;
      const int ch_l = lane_c & 15, q = lane_c >> 4;
      const short8 v = ld16(&Vl[cg * 16 + ch_l][kh * 32 + q * 8]);
      st16(Vf + (fbase + f_l) * 512 + lane_c * 8, v);
    }
  }
}

// ---------------------------------------------------------------------------
// Kernel 2: flash attention + fused out-proj, PRODUCER-CONSUMER SPECIALIZED.
// 256 blocks x 512 thr, 64 rows, LDP=80, Pl[2] -- proven geometry.
// Waves 0-3 (producers): wave p owns rows [16p,16p+16): S = 4 MFMA over all
//   64 keys, exp/cvt_pk, P-store; K prefetch 2 ahead. Waves 4-7 (consumers):
//   wave c owns ch [64c,64c+64): 8 V frags + 8 P b128 reads + 32 PV MFMA.
// Each SIMD hosts 1 producer + 1 consumer (wave%4 mapping) -> exp/VALU runs
// concurrently with PV MFMA by construction instead of phase-serialized
// (R10 counters: MfmaUtil 23 + VALUBusy 33, both pipes idle ~half the time).
// Race discipline unchanged: iter kt reads Pl[kt&1], producers write
// Pl[(kt+1)&1], one barrier/iter. Total MFMA/V-load traffic unchanged;
// P LDS reads HALVE (consumers reuse each P frag across 4 tn).
// setprio(1) on the consumer MFMA cluster = T5 in its proven regime
// (wave role diversity).
// ---------------------------------------------------------------------------
__global__ __launch_bounds__(512, 2)
void flash_kernel(const unsigned short* __restrict__ Qf,
                  const unsigned short* __restrict__ Kf,
                  const unsigned short* __restrict__ Vf,
                  const unsigned short* __restrict__ Wf_o,
                  const void* __restrict__ bo,
                  const void* __restrict__ xin, void* __restrict__ out) {
  __shared__ unsigned short Pl[2][64 * LDP];   // 20.5 KB
  __shared__ unsigned short Ol[64 * LDO];      // 33.8 KB
  __shared__ float Lpr[64];
  __shared__ float Ll[64];
  __shared__ int flagl[8];

  const int t = (int)threadIdx.x;
  const int wave = t >> 6, lane = t & 63, quad = lane >> 4, l15 = lane & 15;

  {
    const int bad = detect_bad((const unsigned short*)xin, t);
    if (lane == 0) flagl[wave] = (__ballot(bad) != 0ull) ? 1 : 0;
  }

  const int raw = (int)blockIdx.x;
  const int b = raw & 3;                 // consecutive blocks spread over XCDs
  const int mt = raw >> 2;
  const long qrow0 = (long)b * 4096 + (long)mt * 64;
  const int isProd = (wave < 4);
  const int p = wave & 3;                // producer row-group / consumer ch-group

  const long kfrag0 = (long)b * 256;
  const long vfrag0 = (long)b * 64 * 32;

  float lpart = 0.0f;
  floatx4 oacc[4][4];
#pragma unroll
  for (int i = 0; i < 4; i++)
#pragma unroll
    for (int j = 0; j < 4; j++) oacc[i][j] = (floatx4)0.0f;

  short8 qf, kb[4];
  if (isProd) {
    qf = ld16(Qf + ((qrow0 >> 4) + p) * 512 + lane * 8);
#pragma unroll
    for (int j = 0; j < 4; j++)
      kb[j] = ld16(Kf + (kfrag0 + j) * 512 + lane * 8);          // K(0)
    {
      floatx4 s[4];
#pragma unroll
      for (int j = 0; j < 4; j++) { s[j] = (floatx4)0.0f; s[j] = MFMA16(kb[j], qf, s[j]); }
      unsigned short* pl = Pl[0];
#pragma unroll
      for (int j = 0; j < 4; j++) {
        const float p0 = exp2f(s[j][0] - PSHIFT);
        const float p1 = exp2f(s[j][1] - PSHIFT);
        const float p2 = exp2f(s[j][2] - PSHIFT);
        const float p3 = exp2f(s[j][3] - PSHIFT);
        lpart += (p0 + p1) + (p2 + p3);
        uintx2 w;
        w[0] = cvt_pk_bf16(p0, p1);
        w[1] = cvt_pk_bf16(p2, p3);
        *(uintx2*)__builtin_assume_aligned(
            &pl[(p * 16 + l15) * LDP + j * 16 + quad * 4], 8) = w;
      }
    }
#pragma unroll
    for (int j = 0; j < 4; j++)
      kb[j] = ld16(Kf + (kfrag0 + 4 + j) * 512 + lane * 8);      // K(1)
  }
  __syncthreads();   // publish P(0) (+ flagl)

  for (int kt = 0; kt < 64; kt++) {
    if (!isProd) {
      // ---- consumer: V frags + P reads + 32 PV MFMA ----
      short8 vb[4][2];
#pragma unroll
      for (int tn = 0; tn < 4; tn++)
#pragma unroll
        for (int kh = 0; kh < 2; kh++)
          vb[tn][kh] = ld16(Vf + (vfrag0 + (long)kt * 32 + (p * 4 + tn) * 2 + kh) * 512 + lane * 8);

      const unsigned short* plr = Pl[kt & 1];
      short8 pa[4][2];
#pragma unroll
      for (int rm = 0; rm < 4; rm++)
#pragma unroll
        for (int kh = 0; kh < 2; kh++)
          pa[rm][kh] = ld16(&plr[(rm * 16 + l15) * LDP + kh * 32 + quad * 8]);

      __builtin_amdgcn_s_setprio(1);
#pragma unroll
      for (int kh = 0; kh < 2; kh++)
#pragma unroll
        for (int tn = 0; tn < 4; tn++)
#pragma unroll
          for (int rm = 0; rm < 4; rm++)
            oacc[rm][tn] = MFMA16(pa[rm][kh], vb[tn][kh], oacc[rm][tn]);
      __builtin_amdgcn_s_setprio(0);
    } else {
      // ---- producer: K(kt+2) prefetch, S(kt+1) -> P store ----
      short8 kbn[4];
      const int kt2 = (kt + 2) & 63;
#pragma unroll
      for (int j = 0; j < 4; j++)
        kbn[j] = ld16(Kf + (kfrag0 + kt2 * 4 + j) * 512 + lane * 8);

      if (kt < 63) {
        floatx4 s[4];
#pragma unroll
        for (int j = 0; j < 4; j++) { s[j] = (floatx4)0.0f; s[j] = MFMA16(kb[j], qf, s[j]); }
        unsigned short* pl = Pl[(kt + 1) & 1];
#pragma unroll
        for (int j = 0; j < 4; j++) {
          const float p0 = exp2f(s[j][0] - PSHIFT);
          const float p1 = exp2f(s[j][1] - PSHIFT);
          const float p2 = exp2f(s[j][2] - PSHIFT);
          const float p3 = exp2f(s[j][3] - PSHIFT);
          lpart += (p0 + p1) + (p2 + p3);
          uintx2 w;
          w[0] = cvt_pk_bf16(p0, p1);
          w[1] = cvt_pk_bf16(p2, p3);
          *(uintx2*)__builtin_assume_aligned(
              &pl[(p * 16 + l15) * LDP + j * 16 + quad * 4], 8) = w;
        }
      }
#pragma unroll
      for (int j = 0; j < 4; j++) kb[j] = kbn[j];
    }
    __syncthreads();   // publish P(kt+1)
  }

  // ---- l reduction (producers own rows; sum over quads) ----
  if (isProd) {
    lpart += __shfl_xor(lpart, 16);
    lpart += __shfl_xor(lpart, 32);
    if (lane < 16) Lpr[p * 16 + lane] = lpart;
  }
  __syncthreads();
  if (t < 64) Ll[t] = 1.0f / Lpr[t];
  __syncthreads();

  // ---- normalize into Ol [row][ch] (consumers hold oacc) ----
  if (!isProd) {
#pragma unroll
    for (int rm = 0; rm < 4; rm++) {
      const floatx4 ll = *(const floatx4*)&Ll[rm * 16 + quad * 4];
#pragma unroll
      for (int tn = 0; tn < 4; tn++)
#pragma unroll
        for (int r = 0; r < 4; r++)
          Ol[(rm * 16 + quad * 4 + r) * LDO + p * 64 + tn * 16 + l15] =
              f2bf(oacc[rm][tn][r] * ll[r]);
    }
  }
  __syncthreads();

  // ---- fused out-projection (all 8 waves; Wf_o frag-major, coalesced) ----
  const int isf32 = flagl[0] | flagl[1] | flagl[2] | flagl[3] |
                    flagl[4] | flagl[5] | flagl[6] | flagl[7];
  const int m2 = wave & 3, gh = wave >> 2;
  floatx4 acc2[8];
#pragma unroll
  for (int i = 0; i < 8; i++) acc2[i] = (floatx4)0.0f;
#pragma unroll
  for (int ks = 0; ks < 8; ks++) {
    const short8 a = ld16(&Ol[(m2 * 16 + l15) * LDO + ks * 32 + quad * 8]);
#pragma unroll
    for (int tn = 0; tn < 8; tn++) {
      const short8 bfr = ld16(Wf_o + (long)((gh * 8 + tn) * 8 + ks) * 512 + lane * 8);
      acc2[tn] = MFMA16(a, bfr, acc2[tn]);
    }
  }
  __syncthreads();   // all Ol A-frag reads done; reuse Ol for pre-residual
#pragma unroll
  for (int tn = 0; tn < 8; tn++) {
    const int g = gh * 128 + tn * 16 + l15;
    const float bias = ld_in(bo, g, isf32);
#pragma unroll
    for (int r = 0; r < 4; r++)
      Ol[(m2 * 16 + quad * 4 + r) * LDO + g] = f2bf(fmaxf(acc2[tn][r] + bias, 0.0f));
  }
  __syncthreads();

  // ---- residual + store, fully coalesced ----
  if (isf32) {
    const float* xf = (const float*)xin + qrow0 * 256;
    float* of = (float*)out + qrow0 * 256;
#pragma unroll
    for (int pp = 0; pp < 8; pp++) {
      const int idx = pp * 2048 + t * 4;
      const int row = idx >> 8, ch = idx & 255;
      floatx4 xv = *(const floatx4*)(xf + idx);
      floatx4 ov;
#pragma unroll
      for (int j = 0; j < 4; j++) ov[j] = bf2f(Ol[row * LDO + ch + j]) + xv[j];
      *(floatx4*)(of + idx) = ov;
    }
  } else {
    const unsigned short* xh = (const unsigned short*)xin + qrow0 * 256;
    unsigned short* oh = (unsigned short*)out + qrow0 * 256;
#pragma unroll
    for (int pp = 0; pp < 4; pp++) {
      const int idx = pp * 4096 + t * 8;
      const int row = idx >> 8, ch = idx & 255;
      const short8 xv = ld16(xh + idx);
      short8 ov;
#pragma unroll
      for (int j = 0; j < 8; j++)
        ov[j] = (short)f2bf(bf2f(Ol[row * LDO + ch + j]) + bf2f((unsigned short)xv[j]));
      st16(oh + idx, ov);
    }
  }
}

extern "C" void kernel_launch(void* const* d_in, const int* in_sizes, int n_in,
                              void* d_out, int out_size, void* d_ws, size_t ws_size,
                              hipStream_t stream) {
  const void* x  = d_in[0];
  const void* Wq = d_in[1]; const void* bq = d_in[2];
  const void* Wk = d_in[3]; const void* bk = d_in[4];
  const void* Wv = d_in[5]; const void* bv = d_in[6];
  const void* Wo = d_in[7]; const void* bo = d_in[8];

  char* ws = (char*)d_ws;
  unsigned short* Qf    = (unsigned short*)ws;              // 1 MB
  unsigned short* Kf    = Qf + (long)4 * 4096 * 32;         // 1 MB
  unsigned short* Vf    = Kf + (long)4 * 4096 * 32;         // 8 MB
  unsigned short* Wf_o  = Vf + (long)4 * 256 * 4096;        // 128 KB
  unsigned short* Wf_v  = Wf_o + (long)128 * 512;           // 128 KB
  unsigned short* Wf_qk = Wf_v + (long)128 * 512;           // 32 KB
  int* flag             = (int*)(Wf_qk + (long)32 * 512);   // 4 B

  prep_kernel<<<36, 256, 0, stream>>>(x, Wq, Wk, Wv, Wo, Wf_qk, Wf_v, Wf_o, flag);
  proj_kernel<<<1280, 256, 0, stream>>>(x, bq, bk, bv, Wf_qk, Wf_v, flag, Qf, Kf, Vf);
  flash_kernel<<<256, 512, 0, stream>>>(Qf, Kf, Vf, Wf_o, bo, x, d_out);
}

// Round 13
// 168.977 us; speedup vs baseline: 1.0225x; 1.0225x over previous
//
#include <hip/hip_runtime.h>

typedef __attribute__((ext_vector_type(8))) short short8;
typedef __attribute__((ext_vector_type(4))) float floatx4;
typedef __attribute__((ext_vector_type(2))) unsigned int uintx2;
typedef __attribute__((ext_vector_type(4))) unsigned int uintx4;

#define MFMA16(a, b, c) __builtin_amdgcn_mfma_f32_16x16x32_bf16((a), (b), (c), 0, 0, 0)

#define LDP 80       // P row stride (ushort); 40 dw == 8 mod 32 (measured best)
#define LDO 264      // O-tile LDS row stride (ushort)
#define LOG2E 1.4426950408889634f
#define PSHIFT 23.083120654223414f  // 16*log2(e); Wq/bq pre-scaled by log2(e)

__device__ __forceinline__ float bf2f(unsigned short u) {
  return __uint_as_float(((unsigned int)u) << 16);
}
__device__ __forceinline__ unsigned short f2bf(float f) {
  unsigned int x = __float_as_uint(f);
  x += 0x7FFFu + ((x >> 16) & 1u);   // RNE; finite inputs
  return (unsigned short)(x >> 16);
}
// packed f32x2 -> bf16x2, RNE (same rounding as f2bf)
__device__ __forceinline__ unsigned int cvt_pk_bf16(float lo, float hi) {
  unsigned int r;
  asm("v_cvt_pk_bf16_f32 %0, %1, %2" : "=v"(r) : "v"(lo), "v"(hi));
  return r;
}
__device__ __forceinline__ float ld_in(const void* p, long i, int isf32) {
  if (isf32) return ((const float*)p)[i];
  return bf2f(((const unsigned short*)p)[i]);
}
__device__ __forceinline__ short8 ld16(const unsigned short* p) {
  return *(const short8*)__builtin_assume_aligned(p, 16);
}
__device__ __forceinline__ void st16(unsigned short* p, short8 v) {
  *(short8*)__builtin_assume_aligned(p, 16) = v;
}
__device__ __forceinline__ int detect_bad(const unsigned short* x, int idx) {
  const short8 v = ld16(x + (long)idx * 8);
  int bad = 0;
#pragma unroll
  for (int j = 0; j < 8; j++) {
    const unsigned int e = (((unsigned short)v[j]) >> 7) & 0xFFu;
    if (e >= 141u) bad = 1;
  }
  return bad;
}

// ===========================================================================
// FRAG-MAJOR layouts (all bf16, 1 KB per fragment, lane-ordered):
//  Qf/Kf: A/B-frag of 16 rows(keys) x 32 ch. frag id = (b*4096+row)/16.
//         addr = fid*512 + lane*8   (lane = quad*16 + l15; l15=row, quad=ch/8)
//  Vf:    B-frag of 16 ch x 32 keys. fid = (b*64+kt)*32 + chgrp*2 + kh.
//  Wf_qk: B-frag 16 out x 32 in. fid = tn*8 + ks  (tn 0..3: Q0,Q1,K0,K1)
//  Wf_v:  B-frag 16 out x 32 in. fid = og*8 + ks  (og 0..15)
//  Wf_o:  B-frag 16 out x 32 in. fid = og*8 + ks  (og 0..15)
// ===========================================================================

// ---------------------------------------------------------------------------
// Kernel 0: one-shot weight prep + isf32 flag publish.
// 36 blocks x 256: 0..15 Wo, 16..31 Wv, 32..35 Wq|Wk (Q pre-scaled log2e).
// ---------------------------------------------------------------------------
__global__ __launch_bounds__(256)
void prep_kernel(const void* __restrict__ x,
                 const void* __restrict__ Wq, const void* __restrict__ Wk,
                 const void* __restrict__ Wv, const void* __restrict__ Wo,
                 unsigned short* __restrict__ Wf_qk,
                 unsigned short* __restrict__ Wf_v,
                 unsigned short* __restrict__ Wf_o,
                 int* __restrict__ flagout) {
  __shared__ unsigned short Vl[64][LDP];
  __shared__ int flagl[4];
  const int t = (int)threadIdx.x;
  const int wave = t >> 6, lane = t & 63;
  {
    const int bad = detect_bad((const unsigned short*)x, t) |
                    detect_bad((const unsigned short*)x, 256 + t);
    if (lane == 0) flagl[wave] = (__ballot(bad) != 0ull) ? 1 : 0;
  }
  __syncthreads();
  const int isf32 = flagl[0] | flagl[1] | flagl[2] | flagl[3];
  if (t == 0) flagout[0] = isf32;   // all blocks write same value -- benign

  const int blk = (int)blockIdx.x;
  const int j = t & 63, r4 = t >> 6;

  if (blk < 32) {            // ---- Wo / Wv: 64out x 64in transpose tiles ----
    const void* W = (blk < 16) ? Wo : Wv;
    unsigned short* dst = (blk < 16) ? Wf_o : Wf_v;
    const int b2 = blk & 15;
    const int g0 = (b2 >> 2) * 64, c0 = (b2 & 3) * 64;   // g0: out, c0: in
#pragma unroll
    for (int k2 = 0; k2 < 16; k2++) {
      const int rr = r4 * 16 + k2;
      Vl[j][rr] = f2bf(ld_in(W, (long)(c0 + rr) * 256 + g0 + j, isf32));
    }
    __syncthreads();
#pragma unroll
    for (int cc = 0; cc < 2; cc++) {
      const int c = t + cc * 256;
      const int f_l = c >> 6, lane_c = c & 63;
      const int og = f_l >> 1, kse = f_l & 1;
      const int out_l = lane_c & 15, q = lane_c >> 4;
      const short8 v = ld16(&Vl[og * 16 + out_l][kse * 32 + q * 8]);
      st16(dst + (long)(((g0 >> 4) + og) * 8 + (c0 >> 5) + kse) * 512 + lane_c * 8, v);
    }
  } else {                   // ---- Wq|Wk combined: 64 "out" x 64 in ----
    const int c0 = (blk - 32) * 64;
#pragma unroll
    for (int k2 = 0; k2 < 16; k2++) {
      const int cl = r4 * 16 + k2;
      const float v = (j < 32) ? ld_in(Wq, (long)(c0 + cl) * 32 + j, isf32) * LOG2E
                               : ld_in(Wk, (long)(c0 + cl) * 32 + (j - 32), isf32);
      Vl[j][cl] = f2bf(v);
    }
    __syncthreads();
#pragma unroll
    for (int cc = 0; cc < 2; cc++) {
      const int c = t + cc * 256;
      const int f_l = c >> 6, lane_c = c & 63;
      const int og = f_l >> 1, kse = f_l & 1;
      const int out_l = lane_c & 15, q = lane_c >> 4;
      const short8 v = ld16(&Vl[og * 16 + out_l][kse * 32 + q * 8]);
      st16(Wf_qk + (long)(og * 8 + (c0 >> 5) + kse) * 512 + lane_c * 8, v);
    }
  }
}

// ---------------------------------------------------------------------------
// Kernel 1: projection — R3 measured-best shape (1280 blocks x 256,
// ct = blk>>8, tile = blk&255), detect replaced by prep's flag.
// ---------------------------------------------------------------------------
__global__ __launch_bounds__(256)
void proj_kernel(const void* __restrict__ x,
                 const void* __restrict__ bq, const void* __restrict__ bk,
                 const void* __restrict__ bv,
                 const unsigned short* __restrict__ Wf_qk,
                 const unsigned short* __restrict__ Wf_v,
                 const int* __restrict__ flag,
                 unsigned short* __restrict__ Qf, unsigned short* __restrict__ Kf,
                 unsigned short* __restrict__ Vf) {
  __shared__ unsigned short Vl[64][LDP];   // transpose buffer
  const int t = (int)threadIdx.x;
  const int wave = t >> 6, lane = t & 63, quad = lane >> 4, l15 = lane & 15;

  const int isf32 = flag[0];

  const int blk = (int)blockIdx.x;
  const int ct = blk >> 8;                      // 0..4
  const long row_base = (long)(blk & 255) * 64; // = b*4096 + n0
  const long arow = row_base + wave * 16 + l15;

  const unsigned short* wb = (ct == 0) ? Wf_qk
                                       : (Wf_v + (long)(ct - 1) * 4 * 8 * 512);

  floatx4 acc[4];
  acc[0] = acc[1] = acc[2] = acc[3] = (floatx4)0.0f;

#pragma unroll
  for (int ks = 0; ks < 8; ks++) {
    short8 a;
    if (isf32) {
      const float* xf = (const float*)x + arow * 256 + ks * 32 + quad * 8;
      const floatx4 f0 = *(const floatx4*)xf;
      const floatx4 f1 = *(const floatx4*)(xf + 4);
      uintx4 u;
      u[0] = cvt_pk_bf16(f0[0], f0[1]); u[1] = cvt_pk_bf16(f0[2], f0[3]);
      u[2] = cvt_pk_bf16(f1[0], f1[1]); u[3] = cvt_pk_bf16(f1[2], f1[3]);
      a = *(short8*)&u;
    } else {
      a = ld16((const unsigned short*)x + arow * 256 + ks * 32 + quad * 8);
    }
#pragma unroll
    for (int tn = 0; tn < 4; tn++) {
      const short8 bfr = ld16(wb + (long)(tn * 8 + ks) * 512 + lane * 8);
      acc[tn] = MFMA16(a, bfr, acc[tn]);
    }
  }

  if (ct == 0) {
    // Vl[row][g]: g 0..31 = Q (log2e-scaled), 32..63 = K
#pragma unroll
    for (int tn = 0; tn < 4; tn++) {
      const int g = tn * 16 + l15;
      const float bias = (g < 32) ? ld_in(bq, g, isf32) * LOG2E
                                  : ld_in(bk, g - 32, isf32);
#pragma unroll
      for (int r = 0; r < 4; r++)
        Vl[wave * 16 + quad * 4 + r][g] = f2bf(fmaxf(acc[tn][r] + bias, 0.0f));
    }
    __syncthreads();
    const long f0 = row_base >> 4;
#pragma unroll
    for (int cc = 0; cc < 2; cc++) {
      const int c = t + cc * 256;                  // 0..511
      const int isK = c >> 8;
      const int c2 = c & 255;
      const int f_l = c2 >> 6, lane_c = c2 & 63;
      const int row_l = lane_c & 15, q = lane_c >> 4;
      const short8 v = ld16(&Vl[f_l * 16 + row_l][isK * 32 + q * 8]);
      unsigned short* dst = isK ? Kf : Qf;
      st16(dst + (f0 + f_l) * 512 + lane_c * 8, v);
    }
  } else {
#pragma unroll
    for (int tn = 0; tn < 4; tn++) {
      const float bias = ld_in(bv, (long)(ct - 1) * 64 + tn * 16 + l15, isf32);
#pragma unroll
      for (int r = 0; r < 4; r++)
        Vl[tn * 16 + l15][wave * 16 + quad * 4 + r] =   // [ch_local][key_local]
            f2bf(fmaxf(acc[tn][r] + bias, 0.0f));
    }
    __syncthreads();
    const long bb = row_base >> 12;
    const int kt = (int)((row_base & 4095) >> 6);
    const long fbase = (bb * 64 + kt) * 32 + (long)(ct - 1) * 8;
#pragma unroll
    for (int cc = 0; cc < 2; cc++) {
      const int c = t * 2 + cc;                    // 0..511
      const int f_l = c >> 6, lane_c = c & 63;
      const int cg = f_l >> 1, kh = f_l & 1;
      const int ch_l = lane_c & 15, q = lane_c >> 4;
      const short8 v = ld16(&Vl[cg * 16 + ch_l][kh * 32 + q * 8]);
      st16(Vf + (fbase + f_l) * 512 + lane_c * 8, v);
    }
  }
}

// ---------------------------------------------------------------------------
// Kernel 2: flash attention + fused out-proj. R6 measured-best structure
// (67.4us: 256 blocks x 512 thr, 64 rows, LDP=80, Pl[2], swapped S
// MFMA(kb,qf), packed cvt_pk P-store, rotated loop, setprio around PV,
// __syncthreads per iter) + ONE new mechanism: V prefetched 1 TILE AHEAD
// (K was already 2 ahead; V was issued and consumed within the same iter,
// ~150cy apart < L2 latency ~250cy -> exposed on every PV entry. The
// barrier's vmcnt(0) drain absorbs V(kt+1) under iter-kt compute.)
// Refuted (ledger): lgkm-only barrier (R3 +4us), 32-bit addressing (R5
// +16us), 512-block re-tile (R7 +23us), 2-tiles/barrier (R8 +5us),
// LDP2=136 (R7), producer-consumer wave split (R12 +7us).
// ---------------------------------------------------------------------------
__global__ __launch_bounds__(512, 2)
void flash_kernel(const unsigned short* __restrict__ Qf,
                  const unsigned short* __restrict__ Kf,
                  const unsigned short* __restrict__ Vf,
                  const unsigned short* __restrict__ Wf_o,
                  const void* __restrict__ bo,
                  const void* __restrict__ xin, void* __restrict__ out) {
  __shared__ unsigned short Pl[2][64 * LDP];   // 20.5 KB
  __shared__ unsigned short Ol[64 * LDO];      // 33.8 KB
  __shared__ float Lp[2][64];
  __shared__ float Ll[64];
  __shared__ int flagl[8];

  const int t = (int)threadIdx.x;
  const int wave = t >> 6, lane = t & 63, quad = lane >> 4, l15 = lane & 15;

  {
    const int bad = detect_bad((const unsigned short*)xin, t);
    if (lane == 0) flagl[wave] = (__ballot(bad) != 0ull) ? 1 : 0;
  }

  const int raw = (int)blockIdx.x;
  const int b = raw & 3;                 // consecutive blocks spread over XCDs
  const int mt = raw >> 2;
  const long qrow0 = (long)b * 4096 + (long)mt * 64;
  const int m = wave & 3, h = wave >> 2;

  const long kfrag0 = (long)b * 256;
  const long vfrag0 = (long)b * 64 * 32;

  const short8 qf = ld16(Qf + ((qrow0 >> 4) + m) * 512 + lane * 8);

  floatx4 oacc[4][2];
#pragma unroll
  for (int i = 0; i < 4; i++) { oacc[i][0] = (floatx4)0.0f; oacc[i][1] = (floatx4)0.0f; }
  float lpart = 0.0f;

  // ---- prologue: V(0) issue; S(0) -> P(0) into Pl[0]; prefetch K(1) ----
  short8 vb[2][2];
#pragma unroll
  for (int tv = 0; tv < 2; tv++)
#pragma unroll
    for (int kh = 0; kh < 2; kh++)
      vb[tv][kh] = ld16(Vf + (vfrag0 + (wave * 2 + tv) * 2 + kh) * 512 + lane * 8);

  short8 kb[2];
#pragma unroll
  for (int i = 0; i < 2; i++)
    kb[i] = ld16(Kf + (kfrag0 + h * 2 + i) * 512 + lane * 8);
  {
    floatx4 s[2];
#pragma unroll
    for (int i = 0; i < 2; i++) { s[i] = (floatx4)0.0f; s[i] = MFMA16(kb[i], qf, s[i]); }
    unsigned short* pl = Pl[0];
#pragma unroll
    for (int i = 0; i < 2; i++) {
      const float p0 = exp2f(s[i][0] - PSHIFT);
      const float p1 = exp2f(s[i][1] - PSHIFT);
      const float p2 = exp2f(s[i][2] - PSHIFT);
      const float p3 = exp2f(s[i][3] - PSHIFT);
      lpart += (p0 + p1) + (p2 + p3);
      uintx2 w;
      w[0] = cvt_pk_bf16(p0, p1);
      w[1] = cvt_pk_bf16(p2, p3);
      *(uintx2*)__builtin_assume_aligned(
          &pl[(m * 16 + l15) * LDP + h * 32 + i * 16 + quad * 4], 8) = w;
    }
  }
#pragma unroll
  for (int i = 0; i < 2; i++)
    kb[i] = ld16(Kf + (kfrag0 + 4 + h * 2 + i) * 512 + lane * 8);
  __syncthreads();   // publish P(0) (+ flagl)

  for (int kt = 0; kt < 64; kt++) {
    // P(kt) fragment reads issued EARLY; latency hides under S/exp below
    const unsigned short* plr = Pl[kt & 1];
    short8 pa[4][2];
#pragma unroll
    for (int rm = 0; rm < 4; rm++)
#pragma unroll
      for (int kh = 0; kh < 2; kh++)
        pa[rm][kh] = ld16(&plr[(rm * 16 + l15) * LDP + kh * 32 + quad * 8]);

    // V(kt+1) prefetch (consumed NEXT iter; drained by this iter's barrier)
    short8 vbn[2][2];
    const int ktv = (kt + 1) & 63;
#pragma unroll
    for (int tv = 0; tv < 2; tv++)
#pragma unroll
      for (int kh = 0; kh < 2; kh++)
        vbn[tv][kh] = ld16(Vf + (vfrag0 + (long)ktv * 32 + (wave * 2 + tv) * 2 + kh) * 512 + lane * 8);

    // K(kt+2) prefetch
    short8 kbn[2];
    const int kt2 = (kt + 2) & 63;
#pragma unroll
    for (int i = 0; i < 2; i++)
      kbn[i] = ld16(Kf + (kfrag0 + kt2 * 4 + h * 2 + i) * 512 + lane * 8);

    // S(kt+1) + packed P(kt+1) write into the other buffer
    if (kt < 63) {
      floatx4 s[2];
#pragma unroll
      for (int i = 0; i < 2; i++) { s[i] = (floatx4)0.0f; s[i] = MFMA16(kb[i], qf, s[i]); }
      unsigned short* pl = Pl[(kt + 1) & 1];
#pragma unroll
      for (int i = 0; i < 2; i++) {
        const float p0 = exp2f(s[i][0] - PSHIFT);
        const float p1 = exp2f(s[i][1] - PSHIFT);
        const float p2 = exp2f(s[i][2] - PSHIFT);
        const float p3 = exp2f(s[i][3] - PSHIFT);
        lpart += (p0 + p1) + (p2 + p3);
        uintx2 w;
        w[0] = cvt_pk_bf16(p0, p1);
        w[1] = cvt_pk_bf16(p2, p3);
        *(uintx2*)__builtin_assume_aligned(
            &pl[(m * 16 + l15) * LDP + h * 32 + i * 16 + quad * 4], 8) = w;
      }
    }
    kb[0] = kbn[0]; kb[1] = kbn[1];

    // PV(kt): 16 MFMA on vb loaded LAST iter; P-writes drain underneath
    __builtin_amdgcn_s_setprio(1);
#pragma unroll
    for (int kh = 0; kh < 2; kh++)
#pragma unroll
      for (int tv = 0; tv < 2; tv++)
#pragma unroll
        for (int rm = 0; rm < 4; rm++)
          oacc[rm][tv] = MFMA16(pa[rm][kh], vb[tv][kh], oacc[rm][tv]);
    __builtin_amdgcn_s_setprio(0);
#pragma unroll
    for (int tv = 0; tv < 2; tv++)
#pragma unroll
      for (int kh = 0; kh < 2; kh++)
        vb[tv][kh] = vbn[tv][kh];
    __syncthreads();   // publish P(kt+1); drains V(kt+1)/K(kt+2)
  }

  // ---- l reduction (lane l15 owns row m*16+l15; sum over quads) ----
  lpart += __shfl_xor(lpart, 16);
  lpart += __shfl_xor(lpart, 32);
  if (lane < 16) Lp[h][m * 16 + lane] = lpart;
  __syncthreads();
  if (t < 64) Ll[t] = 1.0f / (Lp[0][t] + Lp[1][t]);
  __syncthreads();

  // ---- normalize into Ol [row][ch] ----
#pragma unroll
  for (int rm = 0; rm < 4; rm++) {
    const floatx4 ll = *(const floatx4*)&Ll[rm * 16 + quad * 4];
#pragma unroll
    for (int tv = 0; tv < 2; tv++)
#pragma unroll
      for (int r = 0; r < 4; r++)
        Ol[(rm * 16 + quad * 4 + r) * LDO + wave * 32 + tv * 16 + l15] =
            f2bf(oacc[rm][tv][r] * ll[r]);
  }
  __syncthreads();

  // ---- fused out-projection (Wf_o frag-major, coalesced) ----
  const int isf32 = flagl[0] | flagl[1] | flagl[2] | flagl[3] |
                    flagl[4] | flagl[5] | flagl[6] | flagl[7];
  const int m2 = wave & 3, gh = wave >> 2;
  floatx4 acc2[8];
#pragma unroll
  for (int i = 0; i < 8; i++) acc2[i] = (floatx4)0.0f;
#pragma unroll
  for (int ks = 0; ks < 8; ks++) {
    const short8 a = ld16(&Ol[(m2 * 16 + l15) * LDO + ks * 32 + quad * 8]);
#pragma unroll
    for (int tn = 0; tn < 8; tn++) {
      const short8 bfr = ld16(Wf_o + (long)((gh * 8 + tn) * 8 + ks) * 512 + lane * 8);
      acc2[tn] = MFMA16(a, bfr, acc2[tn]);
    }
  }
  __syncthreads();   // all Ol A-frag reads done; reuse Ol for pre-residual
#pragma unroll
  for (int tn = 0; tn < 8; tn++) {
    const int g = gh * 128 + tn * 16 + l15;
    const float bias = ld_in(bo, g, isf32);
#pragma unroll
    for (int r = 0; r < 4; r++)
      Ol[(m2 * 16 + quad * 4 + r) * LDO + g] = f2bf(fmaxf(acc2[tn][r] + bias, 0.0f));
  }
  __syncthreads();

  // ---- residual + store, fully coalesced ----
  if (isf32) {
    const float* xf = (const float*)xin + qrow0 * 256;
    float* of = (float*)out + qrow0 * 256;
#pragma unroll
    for (int p = 0; p < 8; p++) {
      const int idx = p * 2048 + t * 4;
      const int row = idx >> 8, ch = idx & 255;
      floatx4 xv = *(const floatx4*)(xf + idx);
      floatx4 ov;
#pragma unroll
      for (int j = 0; j < 4; j++) ov[j] = bf2f(Ol[row * LDO + ch + j]) + xv[j];
      *(floatx4*)(of + idx) = ov;
    }
  } else {
    const unsigned short* xh = (const unsigned short*)xin + qrow0 * 256;
    unsigned short* oh = (unsigned short*)out + qrow0 * 256;
#pragma unroll
    for (int p = 0; p < 4; p++) {
      const int idx = p * 4096 + t * 8;
      const int row = idx >> 8, ch = idx & 255;
      const short8 xv = ld16(xh + idx);
      short8 ov;
#pragma unroll
      for (int j = 0; j < 8; j++)
        ov[j] = (short)f2bf(bf2f(Ol[row * LDO + ch + j]) + bf2f((unsigned short)xv[j]));
      st16(oh + idx, ov);
    }
  }
}

extern "C" void kernel_launch(void* const* d_in, const int* in_sizes, int n_in,
                              void* d_out, int out_size, void* d_ws, size_t ws_size,
                              hipStream_t stream) {
  const void* x  = d_in[0];
  const void* Wq = d_in[1]; const void* bq = d_in[2];
  const void* Wk = d_in[3]; const void* bk = d_in[4];
  const void* Wv = d_in[5]; const void* bv = d_in[6];
  const void* Wo = d_in[7]; const void* bo = d_in[8];

  char* ws = (char*)d_ws;
  unsigned short* Qf    = (unsigned short*)ws;              // 1 MB
  unsigned short* Kf    = Qf + (long)4 * 4096 * 32;         // 1 MB
  unsigned short* Vf    = Kf + (long)4 * 4096 * 32;         // 8 MB
  unsigned short* Wf_o  = Vf + (long)4 * 256 * 4096;        // 128 KB
  unsigned short* Wf_v  = Wf_o + (long)128 * 512;           // 128 KB
  unsigned short* Wf_qk = Wf_v + (long)128 * 512;           // 32 KB
  int* flag             = (int*)(Wf_qk + (long)32 * 512);   // 4 B

  prep_kernel<<<36, 256, 0, stream>>>(x, Wq, Wk, Wv, Wo, Wf_qk, Wf_v, Wf_o, flag);
  proj_kernel<<<1280, 256, 0, stream>>>(x, bq, bk, bv, Wf_qk, Wf_v, flag, Qf, Kf, Vf);
  flash_kernel<<<256, 512, 0, stream>>>(Qf, Kf, Vf, Wf_o, bo, x, d_out);
}

// Round 14
// 166.083 us; speedup vs baseline: 1.0403x; 1.0174x over previous
//
#include <hip/hip_runtime.h>

typedef __attribute__((ext_vector_type(8))) short short8;
typedef __attribute__((ext_vector_type(4))) float floatx4;
typedef __attribute__((ext_vector_type(2))) unsigned int uintx2;
typedef __attribute__((ext_vector_type(4))) unsigned int uintx4;

#define MFMA16(a, b, c) __builtin_amdgcn_mfma_f32_16x16x32_bf16((a), (b), (c), 0, 0, 0)

#define LDP 80       // P row stride (ushort); 40 dw == 8 mod 32 (measured:
                     // conflicts 5.31M -> 3.21M vs 72; 136 worse, R7)
#define LDO 264      // O-tile LDS row stride (ushort)
#define LOG2E 1.4426950408889634f
#define PSHIFT 23.083120654223414f  // 16*log2(e); Wq/bq pre-scaled by log2(e)

__device__ __forceinline__ float bf2f(unsigned short u) {
  return __uint_as_float(((unsigned int)u) << 16);
}
__device__ __forceinline__ unsigned short f2bf(float f) {
  unsigned int x = __float_as_uint(f);
  x += 0x7FFFu + ((x >> 16) & 1u);   // RNE; finite inputs
  return (unsigned short)(x >> 16);
}
// packed f32x2 -> bf16x2, RNE (same rounding as f2bf)
__device__ __forceinline__ unsigned int cvt_pk_bf16(float lo, float hi) {
  unsigned int r;
  asm("v_cvt_pk_bf16_f32 %0, %1, %2" : "=v"(r) : "v"(lo), "v"(hi));
  return r;
}
__device__ __forceinline__ float ld_in(const void* p, long i, int isf32) {
  if (isf32) return ((const float*)p)[i];
  return bf2f(((const unsigned short*)p)[i]);
}
__device__ __forceinline__ short8 ld16(const unsigned short* p) {
  return *(const short8*)__builtin_assume_aligned(p, 16);
}
__device__ __forceinline__ void st16(unsigned short* p, short8 v) {
  *(short8*)__builtin_assume_aligned(p, 16) = v;
}
__device__ __forceinline__ int detect_bad(const unsigned short* x, int idx) {
  const short8 v = ld16(x + (long)idx * 8);
  int bad = 0;
#pragma unroll
  for (int j = 0; j < 8; j++) {
    const unsigned int e = (((unsigned short)v[j]) >> 7) & 0xFFu;
    if (e >= 141u) bad = 1;
  }
  return bad;
}

// ===========================================================================
// FRAG-MAJOR layouts (all bf16, 1 KB per fragment, lane-ordered):
//  Qf/Kf: A/B-frag of 16 rows(keys) x 32 ch. frag id = (b*4096+row)/16.
//         addr = fid*512 + lane*8   (lane = quad*16 + l15; l15=row, quad=ch/8)
//  Vf:    B-frag of 16 ch x 32 keys. fid = (b*64+kt)*32 + chgrp*2 + kh.
//  Wf_qk: B-frag 16 out x 32 in. fid = tn*8 + ks  (tn 0..3: Q0,Q1,K0,K1)
//  Wf_v:  B-frag 16 out x 32 in. fid = og*8 + ks  (og 0..15)
//  Wf_o:  B-frag 16 out x 32 in. fid = og*8 + ks  (og 0..15)
//
// SESSION LEDGER (refuted flash variants, keep for any successor):
//  lgkm-only barrier (R3 +4us), 32-bit incremental addressing (R5 +16us),
//  merged proj acc[20] (R6 +30us rest), 512-block re-tile (R7 +23us),
//  2-tiles-per-barrier Pl[4] (R8 +5us), LDP2=136 (R7, conflicts up),
//  detect-trim in proj (R10 null), producer-consumer wave split (R12 +7us),
//  V-prefetch 1-ahead (R13 +4us). Champion: this file, 166.5-166.9us total,
//  flash 67.4us @ MfmaUtil 23% / HBM 6.6% -- a structure floor (per-tile
//  S->exp->P->PV chain ~2500cy), NOT a hardware roofline. Exit path would be
//  the fully co-designed 8-phase counted-vmcnt pipeline (T2+T3+T4 graph).
// ===========================================================================

// ---------------------------------------------------------------------------
// Kernel 0: one-shot weight prep + isf32 flag publish.
// 36 blocks x 256: 0..15 Wo, 16..31 Wv, 32..35 Wq|Wk (Q pre-scaled log2e).
// ---------------------------------------------------------------------------
__global__ __launch_bounds__(256)
void prep_kernel(const void* __restrict__ x,
                 const void* __restrict__ Wq, const void* __restrict__ Wk,
                 const void* __restrict__ Wv, const void* __restrict__ Wo,
                 unsigned short* __restrict__ Wf_qk,
                 unsigned short* __restrict__ Wf_v,
                 unsigned short* __restrict__ Wf_o,
                 int* __restrict__ flagout) {
  __shared__ unsigned short Vl[64][LDP];
  __shared__ int flagl[4];
  const int t = (int)threadIdx.x;
  const int wave = t >> 6, lane = t & 63;
  {
    const int bad = detect_bad((const unsigned short*)x, t) |
                    detect_bad((const unsigned short*)x, 256 + t);
    if (lane == 0) flagl[wave] = (__ballot(bad) != 0ull) ? 1 : 0;
  }
  __syncthreads();
  const int isf32 = flagl[0] | flagl[1] | flagl[2] | flagl[3];
  if (t == 0) flagout[0] = isf32;   // all blocks write same value -- benign

  const int blk = (int)blockIdx.x;
  const int j = t & 63, r4 = t >> 6;

  if (blk < 32) {            // ---- Wo / Wv: 64out x 64in transpose tiles ----
    const void* W = (blk < 16) ? Wo : Wv;
    unsigned short* dst = (blk < 16) ? Wf_o : Wf_v;
    const int b2 = blk & 15;
    const int g0 = (b2 >> 2) * 64, c0 = (b2 & 3) * 64;   // g0: out, c0: in
#pragma unroll
    for (int k2 = 0; k2 < 16; k2++) {
      const int rr = r4 * 16 + k2;
      Vl[j][rr] = f2bf(ld_in(W, (long)(c0 + rr) * 256 + g0 + j, isf32));
    }
    __syncthreads();
#pragma unroll
    for (int cc = 0; cc < 2; cc++) {
      const int c = t + cc * 256;
      const int f_l = c >> 6, lane_c = c & 63;
      const int og = f_l >> 1, kse = f_l & 1;
      const int out_l = lane_c & 15, q = lane_c >> 4;
      const short8 v = ld16(&Vl[og * 16 + out_l][kse * 32 + q * 8]);
      st16(dst + (long)(((g0 >> 4) + og) * 8 + (c0 >> 5) + kse) * 512 + lane_c * 8, v);
    }
  } else {                   // ---- Wq|Wk combined: 64 "out" x 64 in ----
    const int c0 = (blk - 32) * 64;
#pragma unroll
    for (int k2 = 0; k2 < 16; k2++) {
      const int cl = r4 * 16 + k2;
      const float v = (j < 32) ? ld_in(Wq, (long)(c0 + cl) * 32 + j, isf32) * LOG2E
                               : ld_in(Wk, (long)(c0 + cl) * 32 + (j - 32), isf32);
      Vl[j][cl] = f2bf(v);
    }
    __syncthreads();
#pragma unroll
    for (int cc = 0; cc < 2; cc++) {
      const int c = t + cc * 256;
      const int f_l = c >> 6, lane_c = c & 63;
      const int og = f_l >> 1, kse = f_l & 1;
      const int out_l = lane_c & 15, q = lane_c >> 4;
      const short8 v = ld16(&Vl[og * 16 + out_l][kse * 32 + q * 8]);
      st16(Wf_qk + (long)(og * 8 + (c0 >> 5) + kse) * 512 + lane_c * 8, v);
    }
  }
}

// ---------------------------------------------------------------------------
// Kernel 1: projection — R3 measured-best shape (1280 blocks x 256,
// ct = blk>>8, tile = blk&255), detect replaced by prep's flag.
// ---------------------------------------------------------------------------
__global__ __launch_bounds__(256)
void proj_kernel(const void* __restrict__ x,
                 const void* __restrict__ bq, const void* __restrict__ bk,
                 const void* __restrict__ bv,
                 const unsigned short* __restrict__ Wf_qk,
                 const unsigned short* __restrict__ Wf_v,
                 const int* __restrict__ flag,
                 unsigned short* __restrict__ Qf, unsigned short* __restrict__ Kf,
                 unsigned short* __restrict__ Vf) {
  __shared__ unsigned short Vl[64][LDP];   // transpose buffer
  const int t = (int)threadIdx.x;
  const int wave = t >> 6, lane = t & 63, quad = lane >> 4, l15 = lane & 15;

  const int isf32 = flag[0];

  const int blk = (int)blockIdx.x;
  const int ct = blk >> 8;                      // 0..4
  const long row_base = (long)(blk & 255) * 64; // = b*4096 + n0
  const long arow = row_base + wave * 16 + l15;

  const unsigned short* wb = (ct == 0) ? Wf_qk
                                       : (Wf_v + (long)(ct - 1) * 4 * 8 * 512);

  floatx4 acc[4];
  acc[0] = acc[1] = acc[2] = acc[3] = (floatx4)0.0f;

#pragma unroll
  for (int ks = 0; ks < 8; ks++) {
    short8 a;
    if (isf32) {
      const float* xf = (const float*)x + arow * 256 + ks * 32 + quad * 8;
      const floatx4 f0 = *(const floatx4*)xf;
      const floatx4 f1 = *(const floatx4*)(xf + 4);
      uintx4 u;
      u[0] = cvt_pk_bf16(f0[0], f0[1]); u[1] = cvt_pk_bf16(f0[2], f0[3]);
      u[2] = cvt_pk_bf16(f1[0], f1[1]); u[3] = cvt_pk_bf16(f1[2], f1[3]);
      a = *(short8*)&u;
    } else {
      a = ld16((const unsigned short*)x + arow * 256 + ks * 32 + quad * 8);
    }
#pragma unroll
    for (int tn = 0; tn < 4; tn++) {
      const short8 bfr = ld16(wb + (long)(tn * 8 + ks) * 512 + lane * 8);
      acc[tn] = MFMA16(a, bfr, acc[tn]);
    }
  }

  if (ct == 0) {
    // Vl[row][g]: g 0..31 = Q (log2e-scaled), 32..63 = K
#pragma unroll
    for (int tn = 0; tn < 4; tn++) {
      const int g = tn * 16 + l15;
      const float bias = (g < 32) ? ld_in(bq, g, isf32) * LOG2E
                                  : ld_in(bk, g - 32, isf32);
#pragma unroll
      for (int r = 0; r < 4; r++)
        Vl[wave * 16 + quad * 4 + r][g] = f2bf(fmaxf(acc[tn][r] + bias, 0.0f));
    }
    __syncthreads();
    const long f0 = row_base >> 4;
#pragma unroll
    for (int cc = 0; cc < 2; cc++) {
      const int c = t + cc * 256;                  // 0..511
      const int isK = c >> 8;
      const int c2 = c & 255;
      const int f_l = c2 >> 6, lane_c = c2 & 63;
      const int row_l = lane_c & 15, q = lane_c >> 4;
      const short8 v = ld16(&Vl[f_l * 16 + row_l][isK * 32 + q * 8]);
      unsigned short* dst = isK ? Kf : Qf;
      st16(dst + (f0 + f_l) * 512 + lane_c * 8, v);
    }
  } else {
#pragma unroll
    for (int tn = 0; tn < 4; tn++) {
      const float bias = ld_in(bv, (long)(ct - 1) * 64 + tn * 16 + l15, isf32);
#pragma unroll
      for (int r = 0; r < 4; r++)
        Vl[tn * 16 + l15][wave * 16 + quad * 4 + r] =   // [ch_local][key_local]
            f2bf(fmaxf(acc[tn][r] + bias, 0.0f));
    }
    __syncthreads();
    const long bb = row_base >> 12;
    const int kt = (int)((row_base & 4095) >> 6);
    const long fbase = (bb * 64 + kt) * 32 + (long)(ct - 1) * 8;
#pragma unroll
    for (int cc = 0; cc < 2; cc++) {
      const int c = t * 2 + cc;                    // 0..511
      const int f_l = c >> 6, lane_c = c & 63;
      const int cg = f_l >> 1, kh = f_l & 1;
      const int ch_l = lane_c & 15, q = lane_c >> 4;
      const short8 v = ld16(&Vl[cg * 16 + ch_l][kh * 32 + q * 8]);
      st16(Vf + (fbase + f_l) * 512 + lane_c * 8, v);
    }
  }
}

// ---------------------------------------------------------------------------
// Kernel 2: flash attention + fused out-proj. CHAMPION (67.4us, reproduced
// R6/R10): 256 blocks x 512 thr, 64 rows, LDP=80, Pl[2], swapped S
// MFMA(kb,qf), packed cvt_pk P-store, rotated loop, K prefetch 2 ahead,
// setprio around PV, __syncthreads per iter.
// ---------------------------------------------------------------------------
__global__ __launch_bounds__(512, 2)
void flash_kernel(const unsigned short* __restrict__ Qf,
                  const unsigned short* __restrict__ Kf,
                  const unsigned short* __restrict__ Vf,
                  const unsigned short* __restrict__ Wf_o,
                  const void* __restrict__ bo,
                  const void* __restrict__ xin, void* __restrict__ out) {
  __shared__ unsigned short Pl[2][64 * LDP];   // 20.5 KB
  __shared__ unsigned short Ol[64 * LDO];      // 33.8 KB
  __shared__ float Lp[2][64];
  __shared__ float Ll[64];
  __shared__ int flagl[8];

  const int t = (int)threadIdx.x;
  const int wave = t >> 6, lane = t & 63, quad = lane >> 4, l15 = lane & 15;

  {
    const int bad = detect_bad((const unsigned short*)xin, t);
    if (lane == 0) flagl[wave] = (__ballot(bad) != 0ull) ? 1 : 0;
  }

  const int raw = (int)blockIdx.x;
  const int b = raw & 3;                 // consecutive blocks spread over XCDs
  const int mt = raw >> 2;
  const long qrow0 = (long)b * 4096 + (long)mt * 64;
  const int m = wave & 3, h = wave >> 2;

  const long kfrag0 = (long)b * 256;
  const long vfrag0 = (long)b * 64 * 32;

  const short8 qf = ld16(Qf + ((qrow0 >> 4) + m) * 512 + lane * 8);

  floatx4 oacc[4][2];
#pragma unroll
  for (int i = 0; i < 4; i++) { oacc[i][0] = (floatx4)0.0f; oacc[i][1] = (floatx4)0.0f; }
  float lpart = 0.0f;

  // ---- prologue: S(0) -> P(0) into Pl[0]; prefetch K(1) ----
  short8 kb[2];
#pragma unroll
  for (int i = 0; i < 2; i++)
    kb[i] = ld16(Kf + (kfrag0 + h * 2 + i) * 512 + lane * 8);
  {
    floatx4 s[2];
#pragma unroll
    for (int i = 0; i < 2; i++) { s[i] = (floatx4)0.0f; s[i] = MFMA16(kb[i], qf, s[i]); }
    unsigned short* pl = Pl[0];
#pragma unroll
    for (int i = 0; i < 2; i++) {
      const float p0 = exp2f(s[i][0] - PSHIFT);
      const float p1 = exp2f(s[i][1] - PSHIFT);
      const float p2 = exp2f(s[i][2] - PSHIFT);
      const float p3 = exp2f(s[i][3] - PSHIFT);
      lpart += (p0 + p1) + (p2 + p3);
      uintx2 w;
      w[0] = cvt_pk_bf16(p0, p1);
      w[1] = cvt_pk_bf16(p2, p3);
      *(uintx2*)__builtin_assume_aligned(
          &pl[(m * 16 + l15) * LDP + h * 32 + i * 16 + quad * 4], 8) = w;
    }
  }
#pragma unroll
  for (int i = 0; i < 2; i++)
    kb[i] = ld16(Kf + (kfrag0 + 4 + h * 2 + i) * 512 + lane * 8);
  __syncthreads();   // publish P(0) (+ flagl)

  for (int kt = 0; kt < 64; kt++) {
    // V frags for THIS tile (vmem, consumed in PV below)
    short8 vb[2][2];
#pragma unroll
    for (int tv = 0; tv < 2; tv++)
#pragma unroll
      for (int kh = 0; kh < 2; kh++)
        vb[tv][kh] = ld16(Vf + (vfrag0 + (long)kt * 32 + (wave * 2 + tv) * 2 + kh) * 512 + lane * 8);

    // P(kt) fragment reads issued EARLY; latency hides under S/exp below
    const unsigned short* plr = Pl[kt & 1];
    short8 pa[4][2];
#pragma unroll
    for (int rm = 0; rm < 4; rm++)
#pragma unroll
      for (int kh = 0; kh < 2; kh++)
        pa[rm][kh] = ld16(&plr[(rm * 16 + l15) * LDP + kh * 32 + quad * 8]);

    // K(kt+2) prefetch
    short8 kbn[2];
    const int kt2 = (kt + 2) & 63;
#pragma unroll
    for (int i = 0; i < 2; i++)
      kbn[i] = ld16(Kf + (kfrag0 + kt2 * 4 + h * 2 + i) * 512 + lane * 8);

    // S(kt+1) + packed P(kt+1) write into the other buffer
    if (kt < 63) {
      floatx4 s[2];
#pragma unroll
      for (int i = 0; i < 2; i++) { s[i] = (floatx4)0.0f; s[i] = MFMA16(kb[i], qf, s[i]); }
      unsigned short* pl = Pl[(kt + 1) & 1];
#pragma unroll
      for (int i = 0; i < 2; i++) {
        const float p0 = exp2f(s[i][0] - PSHIFT);
        const float p1 = exp2f(s[i][1] - PSHIFT);
        const float p2 = exp2f(s[i][2] - PSHIFT);
        const float p3 = exp2f(s[i][3] - PSHIFT);
        lpart += (p0 + p1) + (p2 + p3);
        uintx2 w;
        w[0] = cvt_pk_bf16(p0, p1);
        w[1] = cvt_pk_bf16(p2, p3);
        *(uintx2*)__builtin_assume_aligned(
            &pl[(m * 16 + l15) * LDP + h * 32 + i * 16 + quad * 4], 8) = w;
      }
    }
    kb[0] = kbn[0]; kb[1] = kbn[1];

    // PV(kt): 16 MFMA; P-writes drain underneath, barrier after
    __builtin_amdgcn_s_setprio(1);
#pragma unroll
    for (int kh = 0; kh < 2; kh++)
#pragma unroll
      for (int tv = 0; tv < 2; tv++)
#pragma unroll
        for (int rm = 0; rm < 4; rm++)
          oacc[rm][tv] = MFMA16(pa[rm][kh], vb[tv][kh], oacc[rm][tv]);
    __builtin_amdgcn_s_setprio(0);
    __syncthreads();   // publish P(kt+1)
  }

  // ---- l reduction (lane l15 owns row m*16+l15; sum over quads) ----
  lpart += __shfl_xor(lpart, 16);
  lpart += __shfl_xor(lpart, 32);
  if (lane < 16) Lp[h][m * 16 + lane] = lpart;
  __syncthreads();
  if (t < 64) Ll[t] = 1.0f / (Lp[0][t] + Lp[1][t]);
  __syncthreads();

  // ---- normalize into Ol [row][ch] ----
#pragma unroll
  for (int rm = 0; rm < 4; rm++) {
    const floatx4 ll = *(const floatx4*)&Ll[rm * 16 + quad * 4];
#pragma unroll
    for (int tv = 0; tv < 2; tv++)
#pragma unroll
      for (int r = 0; r < 4; r++)
        Ol[(rm * 16 + quad * 4 + r) * LDO + wave * 32 + tv * 16 + l15] =
            f2bf(oacc[rm][tv][r] * ll[r]);
  }
  __syncthreads();

  // ---- fused out-projection (Wf_o frag-major, coalesced) ----
  const int isf32 = flagl[0] | flagl[1] | flagl[2] | flagl[3] |
                    flagl[4] | flagl[5] | flagl[6] | flagl[7];
  const int m2 = wave & 3, gh = wave >> 2;
  floatx4 acc2[8];
#pragma unroll
  for (int i = 0; i < 8; i++) acc2[i] = (floatx4)0.0f;
#pragma unroll
  for (int ks = 0; ks < 8; ks++) {
    const short8 a = ld16(&Ol[(m2 * 16 + l15) * LDO + ks * 32 + quad * 8]);
#pragma unroll
    for (int tn = 0; tn < 8; tn++) {
      const short8 bfr = ld16(Wf_o + (long)((gh * 8 + tn) * 8 + ks) * 512 + lane * 8);
      acc2[tn] = MFMA16(a, bfr, acc2[tn]);
    }
  }
  __syncthreads();   // all Ol A-frag reads done; reuse Ol for pre-residual
#pragma unroll
  for (int tn = 0; tn < 8; tn++) {
    const int g = gh * 128 + tn * 16 + l15;
    const float bias = ld_in(bo, g, isf32);
#pragma unroll
    for (int r = 0; r < 4; r++)
      Ol[(m2 * 16 + quad * 4 + r) * LDO + g] = f2bf(fmaxf(acc2[tn][r] + bias, 0.0f));
  }
  __syncthreads();

  // ---- residual + store, fully coalesced ----
  if (isf32) {
    const float* xf = (const float*)xin + qrow0 * 256;
    float* of = (float*)out + qrow0 * 256;
#pragma unroll
    for (int p = 0; p < 8; p++) {
      const int idx = p * 2048 + t * 4;
      const int row = idx >> 8, ch = idx & 255;
      floatx4 xv = *(const floatx4*)(xf + idx);
      floatx4 ov;
#pragma unroll
      for (int j = 0; j < 4; j++) ov[j] = bf2f(Ol[row * LDO + ch + j]) + xv[j];
      *(floatx4*)(of + idx) = ov;
    }
  } else {
    const unsigned short* xh = (const unsigned short*)xin + qrow0 * 256;
    unsigned short* oh = (unsigned short*)out + qrow0 * 256;
#pragma unroll
    for (int p = 0; p < 4; p++) {
      const int idx = p * 4096 + t * 8;
      const int row = idx >> 8, ch = idx & 255;
      const short8 xv = ld16(xh + idx);
      short8 ov;
#pragma unroll
      for (int j = 0; j < 8; j++)
        ov[j] = (short)f2bf(bf2f(Ol[row * LDO + ch + j]) + bf2f((unsigned short)xv[j]));
      st16(oh + idx, ov);
    }
  }
}

extern "C" void kernel_launch(void* const* d_in, const int* in_sizes, int n_in,
                              void* d_out, int out_size, void* d_ws, size_t ws_size,
                              hipStream_t stream) {
  const void* x  = d_in[0];
  const void* Wq = d_in[1]; const void* bq = d_in[2];
  const void* Wk = d_in[3]; const void* bk = d_in[4];
  const void* Wv = d_in[5]; const void* bv = d_in[6];
  const void* Wo = d_in[7]; const void* bo = d_in[8];

  char* ws = (char*)d_ws;
  unsigned short* Qf    = (unsigned short*)ws;              // 1 MB
  unsigned short* Kf    = Qf + (long)4 * 4096 * 32;         // 1 MB
  unsigned short* Vf    = Kf + (long)4 * 4096 * 32;         // 8 MB
  unsigned short* Wf_o  = Vf + (long)4 * 256 * 4096;        // 128 KB
  unsigned short* Wf_v  = Wf_o + (long)128 * 512;           // 128 KB
  unsigned short* Wf_qk = Wf_v + (long)128 * 512;           // 32 KB
  int* flag             = (int*)(Wf_qk + (long)32 * 512);   // 4 B

  prep_kernel<<<36, 256, 0, stream>>>(x, Wq, Wk, Wv, Wo, Wf_qk, Wf_v, Wf_o, flag);
  proj_kernel<<<1280, 256, 0, stream>>>(x, bq, bk, bv, Wf_qk, Wf_v, flag, Qf, Kf, Vf);
  flash_kernel<<<256, 512, 0, stream>>>(Qf, Kf, Vf, Wf_o, bo, x, d_out);
}